// Round 8
// baseline (156.116 us; speedup 1.0000x reference)
//
#include <hip/hip_runtime.h>

#define S_LEN 2048
#define HID   1024
#define NHEAD 16
#define NKVH  4
#define HDIM  64
#define NPROJ 1536   // projection output cols: 1024 Q + 256 K + 256 V
#define QKSTR 1280   // qkv buffer row stride: Q(1024) + K(256); V goes to vT transposed

typedef __bf16 bf16x8 __attribute__((ext_vector_type(8)));
typedef float  f32x4  __attribute__((ext_vector_type(4)));

typedef const __attribute__((address_space(1))) void* gas_ptr;
typedef __attribute__((address_space(3))) void*       las_ptr;

// scale = (1/sqrt(1024)) * log2(e): fold softmax scale + base-2 conversion into Q
#define QSCALE 0.04508422f

__device__ __forceinline__ unsigned short f2bf(float f) {
    unsigned u = __builtin_bit_cast(unsigned, f);
    u = u + 0x7FFFu + ((u >> 16) & 1u);   // round-to-nearest-even
    return (unsigned short)(u >> 16);
}

// ---------------- fp32 -> bf16 conversion of x and all weights ----------------
__global__ __launch_bounds__(256) void cvt_all(
    const float* __restrict__ x,  const float* __restrict__ wq,
    const float* __restrict__ wk, const float* __restrict__ wv,
    unsigned short* __restrict__ xbf, unsigned short* __restrict__ wbf)
{
    const long nx  = (long)S_LEN * HID;     // 2097152
    const long nwq = (long)HID * HID;       // 1048576
    const long nwk = (long)256 * HID;       // 262144
    long i = (long)(blockIdx.x * 256 + threadIdx.x) * 4;
    const float* src; unsigned short* dst;
    if (i < nx)                  { src = x  + i;                 dst = xbf + i; }
    else if (i < nx + nwq)       { long j = i - nx;              src = wq + j; dst = wbf + j; }
    else if (i < nx + nwq + nwk) { long j = i - nx - nwq;        src = wk + j; dst = wbf + nwq + j; }
    else                         { long j = i - nx - nwq - nwk;  src = wv + j; dst = wbf + nwq + nwk + j; }
    float4 v = *(const float4*)src;
    ushort4 o; o.x = f2bf(v.x); o.y = f2bf(v.y); o.z = f2bf(v.z); o.w = f2bf(v.w);
    *(ushort4*)dst = o;
}

// ---------------- QKV projection (verified rounds 6-7, byte-identical) ----------------
__global__ __launch_bounds__(256) void proj_gemm(
    const unsigned short* __restrict__ xbf,
    const unsigned short* __restrict__ wbf,
    unsigned short* __restrict__ qkv,
    unsigned short* __restrict__ vT)
{
    __shared__ unsigned short At[2][128 * 64];
    __shared__ unsigned short Bt[2][96 * 64];
    const int tid = threadIdx.x;
    const int w = tid >> 6, l = tid & 63;
    const int quad = l >> 4, lane16 = l & 15;
    const int m0 = blockIdx.y * 128, n0 = blockIdx.x * 96;
    const int wm = (w & 1) * 64, wn = (w >> 1) * 48;

    const int srow = l >> 3;
    const int scol = ((l & 7) ^ srow) * 8;

    f32x4 acc[4][3] = {};

    #define STAGE(KT, BUF)                                                              \
        do {                                                                            \
            _Pragma("unroll")                                                           \
            for (int c = 0; c < 4; ++c) {                                               \
                const int rbase = w * 32 + c * 8;                                       \
                const unsigned short* ga =                                              \
                    xbf + (long)(m0 + rbase + srow) * HID + (KT) + scol;                \
                __builtin_amdgcn_global_load_lds((gas_ptr)ga,                           \
                    (las_ptr)&At[BUF][rbase * 64], 16, 0, 0);                           \
            }                                                                           \
            _Pragma("unroll")                                                           \
            for (int c = 0; c < 3; ++c) {                                               \
                const int rbase = w * 24 + c * 8;                                       \
                const unsigned short* gb =                                              \
                    wbf + (long)(n0 + rbase + srow) * HID + (KT) + scol;                \
                __builtin_amdgcn_global_load_lds((gas_ptr)gb,                           \
                    (las_ptr)&Bt[BUF][rbase * 64], 16, 0, 0);                           \
            }                                                                           \
        } while (0)

    STAGE(0, 0);

    for (int i = 0; i < 16; ++i) {
        const int cur = i & 1;
        __syncthreads();
        if (i + 1 < 16) STAGE((i + 1) * 64, cur ^ 1);

        #pragma unroll
        for (int ks = 0; ks < 2; ++ks) {
            const int swz = ((ks * 4 + quad) ^ (lane16 & 7)) * 8;
            bf16x8 a[4], b[3];
            #pragma unroll
            for (int mi = 0; mi < 4; ++mi)
                a[mi] = *(const bf16x8*)&At[cur][(wm + mi * 16 + lane16) * 64 + swz];
            #pragma unroll
            for (int ni = 0; ni < 3; ++ni)
                b[ni] = *(const bf16x8*)&Bt[cur][(wn + ni * 16 + lane16) * 64 + swz];
            #pragma unroll
            for (int mi = 0; mi < 4; ++mi)
                #pragma unroll
                for (int ni = 0; ni < 3; ++ni)
                    acc[mi][ni] = __builtin_amdgcn_mfma_f32_16x16x32_bf16(a[mi], b[ni], acc[mi][ni], 0, 0, 0);
        }
    }
    #undef STAGE

    #pragma unroll
    for (int mi = 0; mi < 4; ++mi) {
        const int row = m0 + wm + mi * 16 + quad * 4;
        #pragma unroll
        for (int ni = 0; ni < 3; ++ni) {
            const int col = n0 + wn + ni * 16 + lane16;
            #pragma unroll
            for (int r = 0; r < 4; ++r) {
                const float v = acc[mi][ni][r];
                if (col < 1024)
                    qkv[(long)(row + r) * QKSTR + col] = f2bf(v * QSCALE);
                else if (col < 1280)
                    qkv[(long)(row + r) * QKSTR + col] = f2bf(v);
                else
                    vT[(long)(col - 1280) * S_LEN + (row + r)] = f2bf(v);
            }
        }
    }
}

// ---------------- flash attention (MFMA), causal, GQA rep=4 ----------------
// Round-8: barrier-free. K/V fragments gathered DIRECTLY from global in MFMA
// fragment layout (exact index substitution of the former LDS-staged reads;
// each b128 = 16 rows x 64B contiguous chunks -> L1/L2-friendly, high reuse
// across the 4 waves and 4 heads sharing each kv-head). Deletes the K/V LDS
// tiles (80 of 96 KB/iter LDS traffic), all staging latency, and every
// __syncthreads (P buffer is wave-private; ordering verified in round 7).
// Pipeline: V(kt) loads issue at iter top (consumed at PV ~300cyc later);
// K(kt+1) loads issue right after QK (consumed next iter). Manual 2x unroll
// ping-pongs the K register buffer (avoids dynamic register indexing).
#define KSTR 72
__global__ __launch_bounds__(256) void attn(
    const unsigned short* __restrict__ qkv,
    const unsigned short* __restrict__ vT,
    float* __restrict__ out)
{
    __shared__ unsigned short Pb[4 * 16 * KSTR];    // per-wave P [qrow][kv] (swizzled)

    const int tid = threadIdx.x;
    const int w = tid >> 6, l = tid & 63;
    const int quad = l >> 4, lane16 = l & 15;
    const int bx = blockIdx.x, by = blockIdx.y;
    const int qt = (by & 8) ? (31 - bx) : bx;       // balanced pairing remap
    const int h  = by;
    const int kh = h >> 2;
    const int qcol = h * 64;
    const int kcol = 1024 + kh * 64;

    // Q fragments (A-layout: m=lane&15, k=quad*8+j), Q pre-scaled by proj_gemm
    const long qrow = (long)(qt * 64 + w * 16 + lane16);
    bf16x8 qa0 = *(const bf16x8*)&qkv[qrow * QKSTR + qcol + quad * 8];
    bf16x8 qa1 = *(const bf16x8*)&qkv[qrow * QKSTR + qcol + 32 + quad * 8];

    f32x4 o[4] = {};
    float rsum[4] = {0.f, 0.f, 0.f, 0.f};

    unsigned short* pw = &Pb[w * 16 * KSTR];

    #define LOADK(DST, KT)                                                            \
        _Pragma("unroll")                                                             \
        for (int t = 0; t < 4; ++t)                                                   \
            _Pragma("unroll")                                                         \
            for (int ks = 0; ks < 2; ++ks)                                            \
                DST[t][ks] = *(const bf16x8*)&qkv[                                    \
                    (long)((KT) * 64 + t * 16 + lane16) * QKSTR + kcol + ks * 32 + quad * 8];

    #define LOADV(DST, KT)                                                            \
        _Pragma("unroll")                                                             \
        for (int t = 0; t < 4; ++t)                                                   \
            _Pragma("unroll")                                                         \
            for (int ks = 0; ks < 2; ++ks)                                            \
                DST[t][ks] = *(const bf16x8*)&vT[                                     \
                    (long)(kh * 64 + t * 16 + lane16) * S_LEN + (KT) * 64 + ks * 32 + quad * 8];

    #define STEP(KB, KBN, KT)                                                         \
    {                                                                                 \
        bf16x8 vb[4][2];                                                              \
        LOADV(vb, KT);                             /* consumed at PV below */         \
        f32x4 sacc[4] = {};                                                           \
        _Pragma("unroll")                                                             \
        for (int t = 0; t < 4; ++t) {                                                 \
            sacc[t] = __builtin_amdgcn_mfma_f32_16x16x32_bf16(qa0, KB[t][0], sacc[t], 0, 0, 0); \
            sacc[t] = __builtin_amdgcn_mfma_f32_16x16x32_bf16(qa1, KB[t][1], sacc[t], 0, 0, 0); \
        }                                                                             \
        if ((KT) < qt) { LOADK(KBN, (KT) + 1); }   /* consumed next iter */           \
        if ((KT) == qt) {                          /* causal mask, diagonal tile */   \
            _Pragma("unroll")                                                         \
            for (int t = 0; t < 4; ++t) {                                             \
                const int colw = t * 16 + lane16;                                     \
                _Pragma("unroll")                                                     \
                for (int r = 0; r < 4; ++r)                                           \
                    if (colw > w * 16 + quad * 4 + r) sacc[t][r] = -3.0e38f;          \
            }                                                                         \
        }                                                                             \
        _Pragma("unroll")                                                             \
        for (int t = 0; t < 4; ++t)                                                   \
            _Pragma("unroll")                                                         \
            for (int r = 0; r < 4; ++r) {                                             \
                const float p = __builtin_amdgcn_exp2f(sacc[t][r]);                   \
                rsum[r] += p;                                                         \
                const int row = quad * 4 + r;                                         \
                const int col = t * 16 + lane16;                                      \
                pw[row * KSTR + (col ^ ((row & 12) << 1))] = f2bf(p);                 \
            }                                                                         \
        _Pragma("unroll")                                                             \
        for (int ks = 0; ks < 2; ++ks) {                                              \
            bf16x8 pa = *(const bf16x8*)&pw[lane16 * KSTR +                           \
                            ((ks * 32 + quad * 8) ^ ((lane16 & 12) << 1))];           \
            _Pragma("unroll")                                                         \
            for (int t = 0; t < 4; ++t)                                               \
                o[t] = __builtin_amdgcn_mfma_f32_16x16x32_bf16(pa, vb[t][ks], o[t], 0, 0, 0); \
        }                                                                             \
    }

    bf16x8 kba[4][2], kbb[4][2];
    LOADK(kba, 0);
    int kt = 0;
    for (;;) {
        STEP(kba, kbb, kt);
        if (++kt > qt) break;
        STEP(kbb, kba, kt);
        if (++kt > qt) break;
    }
    #undef STEP
    #undef LOADK
    #undef LOADV

    // final row-sum reduce (16 lanes per quad-group) + normalize + store
    float inv[4];
    #pragma unroll
    for (int r = 0; r < 4; ++r) {
        float v = rsum[r];
        v += __shfl_xor(v, 1);
        v += __shfl_xor(v, 2);
        v += __shfl_xor(v, 4);
        v += __shfl_xor(v, 8);
        inv[r] = 1.0f / v;
    }
    const int orow = qt * 64 + w * 16 + quad * 4;
    #pragma unroll
    for (int t = 0; t < 4; ++t) {
        const int col = h * 64 + t * 16 + lane16;
        #pragma unroll
        for (int r = 0; r < 4; ++r)
            out[(long)(orow + r) * (NHEAD * HDIM) + col] = o[t][r] * inv[r];
    }
}

extern "C" void kernel_launch(void* const* d_in, const int* in_sizes, int n_in,
                              void* d_out, int out_size, void* d_ws, size_t ws_size,
                              hipStream_t stream) {
    const float* x  = (const float*)d_in[0];
    const float* wq = (const float*)d_in[1];
    const float* wk = (const float*)d_in[2];
    const float* wv = (const float*)d_in[3];
    float* out = (float*)d_out;

    unsigned short* xbf = (unsigned short*)d_ws;                 // 2048*1024
    unsigned short* wbf = xbf + (size_t)S_LEN * HID;             // 1536*1024
    unsigned short* qkv = wbf + (size_t)NPROJ * HID;             // 2048*1280 (Q+K)
    unsigned short* vT  = qkv + (size_t)S_LEN * QKSTR;           // 256*2048  (V^T)

    cvt_all<<<dim3(3584), dim3(256), 0, stream>>>(x, wq, wk, wv, xbf, wbf);
    proj_gemm<<<dim3(16, 16), dim3(256), 0, stream>>>(xbf, wbf, qkv, vT);
    attn<<<dim3(32, 16), dim3(256), 0, stream>>>(qkv, vT, out);
}

// Round 9
// 128.761 us; speedup vs baseline: 1.2124x; 1.2124x over previous
//
#include <hip/hip_runtime.h>

#define S_LEN 2048
#define HID   1024
#define NHEAD 16
#define NKVH  4
#define HDIM  64
#define NPROJ 1536   // projection output cols: 1024 Q + 256 K + 256 V
#define QKSTR 1280   // qkv buffer row stride: Q(1024) + K(256); V goes to vT transposed
#define PCHUNK 4160  // partial chunk stride in floats: 64*64 O + 64 l

typedef __bf16 bf16x8 __attribute__((ext_vector_type(8)));
typedef float  f32x4  __attribute__((ext_vector_type(4)));

typedef const __attribute__((address_space(1))) void* gas_ptr;
typedef __attribute__((address_space(3))) void*       las_ptr;

// scale = (1/sqrt(1024)) * log2(e): fold softmax scale + base-2 conversion into Q
#define QSCALE 0.04508422f

__device__ __forceinline__ unsigned short f2bf(float f) {
    unsigned u = __builtin_bit_cast(unsigned, f);
    u = u + 0x7FFFu + ((u >> 16) & 1u);   // round-to-nearest-even
    return (unsigned short)(u >> 16);
}

// ---------------- fp32 -> bf16 conversion of x and all weights ----------------
__global__ __launch_bounds__(256) void cvt_all(
    const float* __restrict__ x,  const float* __restrict__ wq,
    const float* __restrict__ wk, const float* __restrict__ wv,
    unsigned short* __restrict__ xbf, unsigned short* __restrict__ wbf)
{
    const long nx  = (long)S_LEN * HID;     // 2097152
    const long nwq = (long)HID * HID;       // 1048576
    const long nwk = (long)256 * HID;       // 262144
    long i = (long)(blockIdx.x * 256 + threadIdx.x) * 4;
    const float* src; unsigned short* dst;
    if (i < nx)                  { src = x  + i;                 dst = xbf + i; }
    else if (i < nx + nwq)       { long j = i - nx;              src = wq + j; dst = wbf + j; }
    else if (i < nx + nwq + nwk) { long j = i - nx - nwq;        src = wk + j; dst = wbf + nwq + j; }
    else                         { long j = i - nx - nwq - nwk;  src = wv + j; dst = wbf + nwq + nwk + j; }
    float4 v = *(const float4*)src;
    ushort4 o; o.x = f2bf(v.x); o.y = f2bf(v.y); o.z = f2bf(v.z); o.w = f2bf(v.w);
    *(ushort4*)dst = o;
}

// ---------------- QKV projection (verified rounds 6-8, byte-identical) ----------------
__global__ __launch_bounds__(256) void proj_gemm(
    const unsigned short* __restrict__ xbf,
    const unsigned short* __restrict__ wbf,
    unsigned short* __restrict__ qkv,
    unsigned short* __restrict__ vT)
{
    __shared__ unsigned short At[2][128 * 64];
    __shared__ unsigned short Bt[2][96 * 64];
    const int tid = threadIdx.x;
    const int w = tid >> 6, l = tid & 63;
    const int quad = l >> 4, lane16 = l & 15;
    const int m0 = blockIdx.y * 128, n0 = blockIdx.x * 96;
    const int wm = (w & 1) * 64, wn = (w >> 1) * 48;

    const int srow = l >> 3;
    const int scol = ((l & 7) ^ srow) * 8;

    f32x4 acc[4][3] = {};

    #define STAGE(KT, BUF)                                                              \
        do {                                                                            \
            _Pragma("unroll")                                                           \
            for (int c = 0; c < 4; ++c) {                                               \
                const int rbase = w * 32 + c * 8;                                       \
                const unsigned short* ga =                                              \
                    xbf + (long)(m0 + rbase + srow) * HID + (KT) + scol;                \
                __builtin_amdgcn_global_load_lds((gas_ptr)ga,                           \
                    (las_ptr)&At[BUF][rbase * 64], 16, 0, 0);                           \
            }                                                                           \
            _Pragma("unroll")                                                           \
            for (int c = 0; c < 3; ++c) {                                               \
                const int rbase = w * 24 + c * 8;                                       \
                const unsigned short* gb =                                              \
                    wbf + (long)(n0 + rbase + srow) * HID + (KT) + scol;                \
                __builtin_amdgcn_global_load_lds((gas_ptr)gb,                           \
                    (las_ptr)&Bt[BUF][rbase * 64], 16, 0, 0);                           \
            }                                                                           \
        } while (0)

    STAGE(0, 0);

    for (int i = 0; i < 16; ++i) {
        const int cur = i & 1;
        __syncthreads();
        if (i + 1 < 16) STAGE((i + 1) * 64, cur ^ 1);

        #pragma unroll
        for (int ks = 0; ks < 2; ++ks) {
            const int swz = ((ks * 4 + quad) ^ (lane16 & 7)) * 8;
            bf16x8 a[4], b[3];
            #pragma unroll
            for (int mi = 0; mi < 4; ++mi)
                a[mi] = *(const bf16x8*)&At[cur][(wm + mi * 16 + lane16) * 64 + swz];
            #pragma unroll
            for (int ni = 0; ni < 3; ++ni)
                b[ni] = *(const bf16x8*)&Bt[cur][(wn + ni * 16 + lane16) * 64 + swz];
            #pragma unroll
            for (int mi = 0; mi < 4; ++mi)
                #pragma unroll
                for (int ni = 0; ni < 3; ++ni)
                    acc[mi][ni] = __builtin_amdgcn_mfma_f32_16x16x32_bf16(a[mi], b[ni], acc[mi][ni], 0, 0, 0);
        }
    }
    #undef STAGE

    #pragma unroll
    for (int mi = 0; mi < 4; ++mi) {
        const int row = m0 + wm + mi * 16 + quad * 4;
        #pragma unroll
        for (int ni = 0; ni < 3; ++ni) {
            const int col = n0 + wn + ni * 16 + lane16;
            #pragma unroll
            for (int r = 0; r < 4; ++r) {
                const float v = acc[mi][ni][r];
                if (col < 1024)
                    qkv[(long)(row + r) * QKSTR + col] = f2bf(v * QSCALE);
                else if (col < 1280)
                    qkv[(long)(row + r) * QKSTR + col] = f2bf(v);
                else
                    vT[(long)(col - 1280) * S_LEN + (row + r)] = f2bf(v);
            }
        }
    }
}

// ---------------- split-K flash attention (partials), causal, GQA rep=4 ----------------
// No-max softmax (rounds 5-8 verified) makes partials additive: each block
// computes O_partial, l_partial over <=8 kv-tiles of one (head, q-tile) and
// writes fp32 partials to ws. 80 chunks/head x 16 heads = 1280 uniform blocks
// = 5 blocks/CU (vs 2 with tail collapse to 1 wave/SIMD in rounds 5-8).
// Internals are the verified round-7 structure: LDS-staged K/V (coalesced
// vector staging), register prefetch, wave-private P with bank swizzle.
#define KSTR 72   // LDS row stride (ushorts): multiple of 8 -> 16B-aligned b128
__global__ __launch_bounds__(256) void attn_part(
    const unsigned short* __restrict__ qkv,
    const unsigned short* __restrict__ vT,
    float* __restrict__ part)
{
    __shared__ unsigned short Kt[64 * KSTR];        // K tile  [kv][d]
    __shared__ unsigned short Vt[64 * KSTR];        // V^T tile [d][kv]
    __shared__ unsigned short Pb[4 * 16 * KSTR];    // per-wave P [qrow][kv] (swizzled)

    const int tid = threadIdx.x;
    const int w = tid >> 6, l = tid & 63;
    const int quad = l >> 4, lane16 = l & 15;
    const int c = blockIdx.x, h = blockIdx.y;

    // chunk -> (qt, ch): per head, qt 0..7 have 1 chunk, 8..15 two, 16..23
    // three, 24..31 four (chunk = ceil((qt+1)/8) pieces of <=8 kv-tiles).
    int qt, ch;
    if (c < 8)       { qt = c;              ch = 0;            }
    else if (c < 24) { qt = 8 + (c - 8) / 2;  ch = (c - 8) % 2;  }
    else if (c < 48) { qt = 16 + (c - 24) / 3; ch = (c - 24) % 3; }
    else             { qt = 24 + (c - 48) / 4; ch = (c - 48) % 4; }
    const int kv0 = ch * 8;
    const int kv1 = min(kv0 + 8, qt + 1);

    const int kh = h >> 2;
    const int qcol = h * 64;
    const int kcol = 1024 + kh * 64;

    // Q fragments (A-layout: m=lane&15, k=quad*8+j), Q pre-scaled by proj_gemm
    const long qrow = (long)(qt * 64 + w * 16 + lane16);
    bf16x8 qa0 = *(const bf16x8*)&qkv[qrow * QKSTR + qcol + quad * 8];
    bf16x8 qa1 = *(const bf16x8*)&qkv[qrow * QKSTR + qcol + 32 + quad * 8];

    f32x4 o[4] = {};
    float rsum[4] = {0.f, 0.f, 0.f, 0.f};

    unsigned short* pw = &Pb[w * 16 * KSTR];

    // staging coords: 256 thr x 16 ushorts cover each 64x64 tile
    const int sr = tid >> 2, ss = tid & 3;
    const long vrow = (long)(kh * 64 + sr) * S_LEN;

    // prologue: prefetch first tile into registers
    bf16x8 kr0, kr1, vr0, vr1;
    {
        const long gk = (long)(kv0 * 64 + sr) * QKSTR + kcol + ss * 16;
        kr0 = *(const bf16x8*)&qkv[gk];
        kr1 = *(const bf16x8*)&qkv[gk + 8];
        const long gv = vrow + kv0 * 64 + ss * 16;
        vr0 = *(const bf16x8*)&vT[gv];
        vr1 = *(const bf16x8*)&vT[gv + 8];
    }

    for (int kt = kv0; kt < kv1; ++kt) {
        __syncthreads();                      // (A) prev iter's K/V reads done
        *(bf16x8*)&Kt[sr * KSTR + ss * 16]     = kr0;
        *(bf16x8*)&Kt[sr * KSTR + ss * 16 + 8] = kr1;
        *(bf16x8*)&Vt[sr * KSTR + ss * 16]     = vr0;
        *(bf16x8*)&Vt[sr * KSTR + ss * 16 + 8] = vr1;
        if (kt + 1 < kv1) {                   // prefetch next tile (uniform)
            const long gk = (long)((kt + 1) * 64 + sr) * QKSTR + kcol + ss * 16;
            kr0 = *(const bf16x8*)&qkv[gk];
            kr1 = *(const bf16x8*)&qkv[gk + 8];
            const long gv = vrow + (kt + 1) * 64 + ss * 16;
            vr0 = *(const bf16x8*)&vT[gv];
            vr1 = *(const bf16x8*)&vT[gv + 8];
        }
        __syncthreads();                      // (B) staging visible

        // S = Q K^T  (16 q-rows x 64 kv);  B-layout: n=lane&15, k=quad*8+j
        f32x4 sacc[4] = {};
        #pragma unroll
        for (int t = 0; t < 4; ++t) {
            bf16x8 kb0 = *(const bf16x8*)&Kt[(t * 16 + lane16) * KSTR + quad * 8];
            bf16x8 kb1 = *(const bf16x8*)&Kt[(t * 16 + lane16) * KSTR + 32 + quad * 8];
            sacc[t] = __builtin_amdgcn_mfma_f32_16x16x32_bf16(qa0, kb0, sacc[t], 0, 0, 0);
            sacc[t] = __builtin_amdgcn_mfma_f32_16x16x32_bf16(qa1, kb1, sacc[t], 0, 0, 0);
        }

        // causal mask on diagonal tile (C layout: row=quad*4+r, col=t*16+lane16)
        if (kt == qt) {
            #pragma unroll
            for (int t = 0; t < 4; ++t) {
                const int colw = t * 16 + lane16;
                #pragma unroll
                for (int r = 0; r < 4; ++r)
                    if (colw > w * 16 + quad * 4 + r) sacc[t][r] = -3.0e38f;
            }
        }

        // p = exp2(s) directly (scores bounded; masked -> +0). Per-lane
        // row-sum partials; P to per-wave LDS with bank swizzle.
        #pragma unroll
        for (int t = 0; t < 4; ++t)
            #pragma unroll
            for (int r = 0; r < 4; ++r) {
                const float p = __builtin_amdgcn_exp2f(sacc[t][r]);
                rsum[r] += p;
                const int row = quad * 4 + r;
                const int col = t * 16 + lane16;
                pw[row * KSTR + (col ^ ((row & 12) << 1))] = f2bf(p);
            }

        // no barrier: pw is wave-private (round-7 verified ordering)

        // O += P V   (A = P [m=qrow][k=kv], B = V^T [n=d][k=kv])
        #pragma unroll
        for (int ks = 0; ks < 2; ++ks) {
            bf16x8 pa = *(const bf16x8*)&pw[lane16 * KSTR + ((ks * 32 + quad * 8) ^ ((lane16 & 12) << 1))];
            #pragma unroll
            for (int t = 0; t < 4; ++t) {
                bf16x8 vb = *(const bf16x8*)&Vt[(t * 16 + lane16) * KSTR + ks * 32 + quad * 8];
                o[t] = __builtin_amdgcn_mfma_f32_16x16x32_bf16(pa, vb, o[t], 0, 0, 0);
            }
        }
    }

    // epilogue: write unnormalized partial O and per-row l
    float* pb = part + ((long)((h * 32 + qt) * 4 + ch)) * PCHUNK;
    const int rl = w * 16 + quad * 4;                 // wave-local row base
    #pragma unroll
    for (int t = 0; t < 4; ++t) {
        const int col = t * 16 + lane16;
        #pragma unroll
        for (int r = 0; r < 4; ++r)
            pb[(rl + r) * 64 + col] = o[t][r];
    }
    #pragma unroll
    for (int r = 0; r < 4; ++r) {
        float v = rsum[r];
        v += __shfl_xor(v, 1);
        v += __shfl_xor(v, 2);
        v += __shfl_xor(v, 4);
        v += __shfl_xor(v, 8);
        if (lane16 == 0) pb[4096 + rl + r] = v;       // lanes 0,16,32,48
    }
}

// ---------------- combine partials: out = (sum O_c) / (sum l_c) ----------------
__global__ __launch_bounds__(256) void attn_reduce(
    const float* __restrict__ part, float* __restrict__ out)
{
    const int qt = blockIdx.x, h = blockIdx.y;
    const int nch = (qt < 8) ? 1 : (qt < 16) ? 2 : (qt < 24) ? 3 : 4;
    const float* pb = part + ((long)(h * 32 + qt) * 4) * PCHUNK;

    const int tid = threadIdx.x;
    const int row = tid >> 2, colb = (tid & 3) * 16;

    float lsum = 0.0f;
    for (int cc = 0; cc < nch; ++cc) lsum += pb[cc * PCHUNK + 4096 + row];
    const float inv = 1.0f / lsum;

    float4 acc[4] = {};
    for (int cc = 0; cc < nch; ++cc) {
        const float* src = &pb[cc * PCHUNK + row * 64 + colb];
        #pragma unroll
        for (int j = 0; j < 4; ++j) {
            float4 v = *(const float4*)&src[j * 4];
            acc[j].x += v.x; acc[j].y += v.y; acc[j].z += v.z; acc[j].w += v.w;
        }
    }
    float* dst = &out[(long)(qt * 64 + row) * (NHEAD * HDIM) + h * 64 + colb];
    #pragma unroll
    for (int j = 0; j < 4; ++j) {
        float4 v; v.x = acc[j].x * inv; v.y = acc[j].y * inv;
        v.z = acc[j].z * inv; v.w = acc[j].w * inv;
        *(float4*)&dst[j * 4] = v;
    }
}

extern "C" void kernel_launch(void* const* d_in, const int* in_sizes, int n_in,
                              void* d_out, int out_size, void* d_ws, size_t ws_size,
                              hipStream_t stream) {
    const float* x  = (const float*)d_in[0];
    const float* wq = (const float*)d_in[1];
    const float* wk = (const float*)d_in[2];
    const float* wv = (const float*)d_in[3];
    float* out = (float*)d_out;

    unsigned short* xbf = (unsigned short*)d_ws;                 // 2048*1024
    unsigned short* wbf = xbf + (size_t)S_LEN * HID;             // 1536*1024
    unsigned short* qkv = wbf + (size_t)NPROJ * HID;             // 2048*1280 (Q+K)
    unsigned short* vT  = qkv + (size_t)S_LEN * QKSTR;           // 256*2048  (V^T)
    float* part = (float*)(vT + (size_t)256 * S_LEN);            // 16*32*4*4160 fp32

    cvt_all<<<dim3(3584), dim3(256), 0, stream>>>(x, wq, wk, wv, xbf, wbf);
    proj_gemm<<<dim3(16, 16), dim3(256), 0, stream>>>(xbf, wbf, qkv, vT);
    attn_part<<<dim3(80, 16), dim3(256), 0, stream>>>(qkv, vT, part);
    attn_reduce<<<dim3(32, 16), dim3(256), 0, stream>>>(part, out);
}